// Round 12
// baseline (79.014 us; speedup 1.0000x reference)
//
#include <hip/hip_runtime.h>

namespace {

typedef float v2f __attribute__((ext_vector_type(2)));
__device__ __forceinline__ v2f mk2(float a, float b) { v2f r; r.x = a; r.y = b; return r; }

constexpr int NB = 4, ND = 128, NH = 192, NW = 192;
constexpr int PLI = NH * NW;
constexpr int CD = 16;     // output planes per block; 128/16 = 8 exact
constexpr int LDSW = 194;  // 1 left pad + 192 + 1 right pad
constexpr int ROWS = 7;    // 6 staged rows + 1 zero row (h-redirect target)
constexpr int POFF = 2 * ROWS * LDSW;  // parity stride in floats (byte imm 10864)

__global__ __launch_bounds__(256, 2)
void edge_loss3d(const float* __restrict__ pred,
                 const float* __restrict__ targ,
                 float* __restrict__ out)
{
    const int lane = threadIdx.x & 63;
    const int wid  = threadIdx.x >> 6;
    const int d0   = blockIdx.x * CD;
    const int h0   = blockIdx.y * 4;          // block's 4 output rows h0..h0+3
    const int b    = blockIdx.z;

    __shared__ float arena[2][2][ROWS][LDSW]; // [parity][tensor][row][w]
    __shared__ float wsum[4];

    // zero rows (row 6 of every parity/tensor) + w-pads of the 24 data rows
    for (int i = threadIdx.x; i < LDSW; i += 256) {
        arena[0][0][6][i] = 0.f; arena[0][1][6][i] = 0.f;
        arena[1][0][6][i] = 0.f; arena[1][1][6][i] = 0.f;
    }
    if (threadIdx.x < 48) {
        const int s = threadIdx.x / 24, t = (threadIdx.x / 12) & 1;
        const int r = (threadIdx.x % 12) / 2, e = threadIdx.x & 1;
        arena[s][t][r][e * (LDSW - 1)] = 0.f;
    }

    // staging role: wave stages tensor tw, rows rbase..rbase+2 (row idx 0 <-> h0-1)
    const int tw = wid >> 1;
    const int rbase = (wid & 1) * 3;
    const float* sbd = (tw ? targ : pred) + (size_t)b * ND * PLI + lane;

    // clamped source row offsets (clamped rows are never read back: h-redirect)
    const int hh0 = h0 - 1 + rbase, hh2 = hh0 + 2;
    const int ro0 = (hh0 < 0 ? 0 : hh0) * NW;
    const int ro1 = (hh0 + 1) * NW;
    const int ro2 = (hh2 > NH - 1 ? NH - 1 : hh2) * NW;

    // compute-side read pointers (parity 0; parity 1 = +POFF literal offset).
    // h-boundary rows redirect to the zero row (row 6) of the SAME tensor,
    // which exists in both parities at the same +POFF distance.
    const bool vlo = (h0 + wid - 1) >= 0;
    const bool vhi = (h0 + wid + 1) < NH;
    const int ci = 1 + 3 * lane;
    const float* ldp0 = vlo ? &arena[0][0][wid][ci]     : &arena[0][0][6][ci];
    const float* ldp1 =       &arena[0][0][wid + 1][ci];
    const float* ldp2 = vhi ? &arena[0][0][wid + 2][ci] : &arena[0][0][6][ci];
    const float* ldt0 = vlo ? &arena[0][1][wid][ci]     : &arena[0][1][6][ci];
    const float* ldt1 =       &arena[0][1][wid + 1][ci];
    const float* ldt2 = vhi ? &arena[0][1][wid + 2][ci] : &arena[0][1][6][ci];

    // rolling state (literal indices only; ~57 floats + pointers)
    v2f   qa[2][3][3];
    float qc[2][3][3];
    v2f   accA = mk2(0.f, 0.f);
    float acc2 = 0.f;

#define RPTR(T, RR) ((T) ? ((RR) == 0 ? ldt0 : (RR) == 1 ? ldt1 : ldt2)       \
                         : ((RR) == 0 ? ldp0 : (RR) == 1 ? ldp1 : ldp2))

// one async 256B row-chunk: global (per-lane) -> LDS (uniform base + lane*4)
#define DMA1(S, R, GP, C)                                                     \
    __builtin_amdgcn_global_load_lds(                                         \
        (const __attribute__((address_space(1))) void*)((GP) + 64 * (C)),     \
        (__attribute__((address_space(3))) void*)&arena[S][tw][rbase + (R)][1 + 64 * (C)], \
        4, 0, 0)

// stage plane P (in range) into parity S: 9 DMA issues, zero registers
#define STAGE(S, P) do {                                                      \
    const float* g0_ = sbd + (P) * PLI + ro0;                                 \
    const float* g1_ = sbd + (P) * PLI + ro1;                                 \
    const float* g2_ = sbd + (P) * PLI + ro2;                                 \
    DMA1(S, 0, g0_, 0); DMA1(S, 0, g0_, 1); DMA1(S, 0, g0_, 2);               \
    DMA1(S, 1, g1_, 0); DMA1(S, 1, g1_, 1); DMA1(S, 1, g1_, 2);               \
    DMA1(S, 2, g2_, 0); DMA1(S, 2, g2_, 1); DMA1(S, 2, g2_, 2);               \
} while (0)

// edge planes (d0-1, d0+16 at grid ends): wave-uniform zero-fill instead
#define STAGE_Z(S, P) do {                                                    \
    if ((P) >= 0 && (P) < ND) { STAGE(S, P); }                                \
    else {                                                                    \
        float* z0_ = &arena[S][tw][rbase + 0][1] + lane;                      \
        float* z1_ = &arena[S][tw][rbase + 1][1] + lane;                      \
        float* z2_ = &arena[S][tw][rbase + 2][1] + lane;                      \
        z0_[0] = 0.f; z0_[64] = 0.f; z0_[128] = 0.f;                          \
        z1_[0] = 0.f; z1_[64] = 0.f; z1_[128] = 0.f;                          \
        z2_[0] = 0.f; z2_[64] = 0.f; z2_[128] = 0.f;                          \
    }                                                                         \
} while (0)

// one h-row pass of tensor T, parity S, into slot SP; packed (j0,j1) + scalar j2
#define ROWPASS(T, SP, RR, S) do {                                            \
    const float* rp_ = RPTR(T, RR) + (S) * POFF;                              \
    const float xm_ = rp_[-1], x0_ = rp_[0], x1_ = rp_[1], x2_ = rp_[2], xp_ = rp_[3]; \
    const v2f L_ = mk2(xm_, x0_), M_ = mk2(x0_, x1_), R_ = mk2(x1_, x2_);     \
    const v2f   sA_ = (L_ + R_ + 2.f * M_) * 0.25f;                           \
    const float s2_ = (x1_ + xp_ + 2.f * x2_) * 0.25f;                        \
    const v2f   tA_ = R_ - L_;                                                \
    const float t2_ = xp_ - x1_;                                              \
    if ((RR) == 0) {                                                          \
        qa[T][SP][0] = 0.25f * sA_;  qc[T][SP][0] = 0.25f * s2_;              \
        qa[T][SP][1] = -sA_;         qc[T][SP][1] = -s2_;                     \
        qa[T][SP][2] = 0.25f * tA_;  qc[T][SP][2] = 0.25f * t2_;              \
    } else if ((RR) == 1) {                                                   \
        qa[T][SP][0] += 0.5f * sA_;  qc[T][SP][0] += 0.5f * s2_;              \
        /* sobel_h center weight = 0 -> ts unchanged */                       \
        qa[T][SP][2] += 0.5f * tA_;  qc[T][SP][2] += 0.5f * t2_;              \
    } else {                                                                  \
        qa[T][SP][0] += 0.25f * sA_; qc[T][SP][0] += 0.25f * s2_;             \
        qa[T][SP][1] += sA_;         qc[T][SP][1] += s2_;                     \
        qa[T][SP][2] += 0.25f * tA_; qc[T][SP][2] += 0.25f * t2_;             \
    }                                                                         \
} while (0)

#define ROW6(SP, S) do {                                                      \
    ROWPASS(0, SP, 0, S); ROWPASS(0, SP, 1, S); ROWPASS(0, SP, 2, S);         \
    ROWPASS(1, SP, 0, S); ROWPASS(1, SP, 1, S); ROWPASS(1, SP, 2, S);         \
} while (0)

// single per-phase fence: drain own DMA (had a full compute phase of slack)
// + own ds ops, then barrier. No mid-phase drain.
#define FENCE() do {                                                          \
    asm volatile("s_waitcnt vmcnt(0) lgkmcnt(0)" ::: "memory");               \
    __builtin_amdgcn_s_barrier();                                             \
} while (0)

#define EDGEPK(T, SM, SC, SP, EA, E2) do {                                    \
    const v2f   gxA_ = (qa[T][SM][2] + qa[T][SP][2] + 2.f * qa[T][SC][2]) * 0.25f; \
    const float gx2_ = (qc[T][SM][2] + qc[T][SP][2] + 2.f * qc[T][SC][2]) * 0.25f; \
    const v2f   gyA_ = (qa[T][SM][1] + qa[T][SP][1] + 2.f * qa[T][SC][1]) * 0.25f; \
    const float gy2_ = (qc[T][SM][1] + qc[T][SP][1] + 2.f * qc[T][SC][1]) * 0.25f; \
    const v2f   gzA_ = qa[T][SP][0] - qa[T][SM][0];                           \
    const float gz2_ = qc[T][SP][0] - qc[T][SM][0];                           \
    const v2f   dA_ = gxA_ * gxA_ + gyA_ * gyA_ + gzA_ * gzA_ + 1e-8f;        \
    const float d2_ = gx2_ * gx2_ + gy2_ * gy2_ + gz2_ * gz2_ + 1e-8f;        \
    EA = mk2(sqrtf(dA_.x), sqrtf(dA_.y));                                     \
    E2 = sqrtf(d2_);                                                          \
} while (0)

#define EMIT(SM, SC, SP) do {                                                 \
    v2f eA0_, eA1_; float e20_, e21_;                                         \
    EDGEPK(0, SM, SC, SP, eA0_, e20_);                                        \
    EDGEPK(1, SM, SC, SP, eA1_, e21_);                                        \
    const v2f dfA_ = eA0_ - eA1_;                                             \
    accA += mk2(fabsf(dfA_.x), fabsf(dfA_.y));                                \
    acc2 += fabsf(e20_ - e21_);                                               \
} while (0)

    // phase k = 0..17 consumes plane d0-1+k from parity k%2 (slot k%3) and
    // stages plane d0+k into parity (k+1)%2. One fence per phase.
    STAGE_Z(0, d0 - 1);
    FENCE();

    STAGE(1, d0);                                         // k=0
    ROW6(0, 0);
    FENCE();
    STAGE(0, d0 + 1);                                     // k=1
    ROW6(1, 1);
    FENCE();

    for (int gg = 0; gg < 2; ++gg) {                      // k=2..13
        const int pp = d0 + 6 * gg;
        STAGE(1, pp + 2); ROW6(2, 0); EMIT(0, 1, 2); FENCE();
        STAGE(0, pp + 3); ROW6(0, 1); EMIT(1, 2, 0); FENCE();
        STAGE(1, pp + 4); ROW6(1, 0); EMIT(2, 0, 1); FENCE();
        STAGE(0, pp + 5); ROW6(2, 1); EMIT(0, 1, 2); FENCE();
        STAGE(1, pp + 6); ROW6(0, 0); EMIT(1, 2, 0); FENCE();
        STAGE(0, pp + 7); ROW6(1, 1); EMIT(2, 0, 1); FENCE();
    }

    STAGE(1, d0 + 14);   ROW6(2, 0); EMIT(0, 1, 2); FENCE();  // k=14
    STAGE(0, d0 + 15);   ROW6(0, 1); EMIT(1, 2, 0); FENCE();  // k=15
    STAGE_Z(1, d0 + 16); ROW6(1, 0); EMIT(2, 0, 1); FENCE();  // k=16
    ROW6(2, 1);          EMIT(0, 1, 2);                        // k=17

#undef RPTR
#undef DMA1
#undef STAGE
#undef STAGE_Z
#undef ROWPASS
#undef ROW6
#undef FENCE
#undef EDGEPK
#undef EMIT

    // wave reduce -> block reduce -> one atomic per block
    float acc = accA.x + accA.y + acc2;
    #pragma unroll
    for (int off = 32; off > 0; off >>= 1)
        acc += __shfl_down(acc, off, 64);
    if (lane == 0) wsum[wid] = acc;
    __syncthreads();
    if (threadIdx.x == 0) {
        const float invN = 1.f / (float)((long long)NB * ND * NH * NW);
        atomicAdd(out, (wsum[0] + wsum[1] + wsum[2] + wsum[3]) * invN);
    }
}

} // namespace

extern "C" void kernel_launch(void* const* d_in, const int* in_sizes, int n_in,
                              void* d_out, int out_size, void* d_ws, size_t ws_size,
                              hipStream_t stream) {
    const float* pred = (const float*)d_in[0];
    const float* targ = (const float*)d_in[1];
    float* out = (float*)d_out;
    (void)in_sizes; (void)n_in; (void)out_size; (void)d_ws; (void)ws_size;

    hipMemsetAsync(out, 0, sizeof(float), stream);

    dim3 grid(ND / CD, NH / 4, NB);   // (8, 48, 4) = 1536 blocks, 6/CU
    dim3 block(256);
    edge_loss3d<<<grid, block, 0, stream>>>(pred, targ, out);
}

// Round 13
// 49.480 us; speedup vs baseline: 1.5969x; 1.5969x over previous
//
#include <hip/hip_runtime.h>

namespace {

constexpr int NB = 4, ND = 128, NH = 192, NW = 192;
constexpr int PLI = NH * NW;
constexpr int CD = 16;    // output planes per block; 128/16 = 8 exact
constexpr int LDSW = 194; // 1 left pad + 192 + 1 right pad

__global__ __launch_bounds__(256, 2)
void edge_loss3d(const float* __restrict__ pred,
                 const float* __restrict__ targ,
                 float* __restrict__ out)
{
    const int lane = threadIdx.x & 63;
    const int wid  = threadIdx.x >> 6;
    const int d0   = blockIdx.x * CD;
    const int h0   = blockIdx.y * 4;          // block's 4 output rows h0..h0+3
    const int b    = blockIdx.z;

    __shared__ float lds[2][6][LDSW];
    __shared__ float zrow[LDSW];
    __shared__ float wsum[4];

    // zero pads + zero-row once (first read is after phase-0 barriers)
    if (threadIdx.x < LDSW) zrow[threadIdx.x] = 0.f;
    if (threadIdx.x < 24) {
        const int t = threadIdx.x / 12, r = (threadIdx.x % 12) / 2, s = threadIdx.x & 1;
        lds[t][r][s * (LDSW - 1)] = 0.f;
    }

    // staging role: wave stages tensor tw, staged rows rbase..rbase+2 (idx 0 <-> h0-1)
    const int tw = wid >> 1;
    const int rbase = (wid & 1) * 3;
    const float* sb = (tw ? targ : pred) + (size_t)b * ND * PLI + 3 * lane;

    // clamped row offsets for staging loads (garbage rows are never read back)
    const int hh0 = h0 - 1 + rbase, hh1 = hh0 + 1, hh2 = hh0 + 2;
    const int ro0 = (hh0 < 0 ? 0 : (hh0 > NH - 1 ? NH - 1 : hh0)) * NW;
    const int ro1 = (hh1 < 0 ? 0 : (hh1 > NH - 1 ? NH - 1 : hh1)) * NW;
    const int ro2 = (hh2 < 0 ? 0 : (hh2 > NH - 1 ? NH - 1 : hh2)) * NW;

    float* ldw = &lds[tw][rbase][1 + 3 * lane];

    // read pointers with zero-row redirect (h-boundary handled here, no masks)
    const bool vlo = (h0 + wid - 1) >= 0;
    const bool vhi = (h0 + wid + 1) < NH;
    const float* zz   = &zrow[1 + 3 * lane];
    const float* ldp0 = vlo ? &lds[0][wid][1 + 3 * lane]     : zz;
    const float* ldp1 =       &lds[0][wid + 1][1 + 3 * lane];
    const float* ldp2 = vhi ? &lds[0][wid + 2][1 + 3 * lane] : zz;
    const float* ldt0 = vlo ? &lds[1][wid][1 + 3 * lane]     : zz;
    const float* ldt1 =       &lds[1][wid + 1][1 + 3 * lane];
    const float* ldt2 = vhi ? &lds[1][wid + 2][1 + 3 * lane] : zz;

    // in-flight staged rows (9 scalars) + rolling UNSCALED conv state
    // q[tensor][slot][kind 0=ss 1=ts 2=st][w] — literal indices only
    float g00, g01, g02, g10, g11, g12, g20, g21, g22;
    float q[2][3][3][3];
    float acc = 0.f;

#define RPTR(T, RR) ((T) ? ((RR) == 0 ? ldt0 : (RR) == 1 ? ldt1 : ldt2)       \
                         : ((RR) == 0 ? ldp0 : (RR) == 1 ? ldp1 : ldp2))

#define PREFETCH(P) do {                                                      \
    const int o_ = (P) * PLI;                                                 \
    g00 = sb[o_ + ro0]; g01 = sb[o_ + ro0 + 1]; g02 = sb[o_ + ro0 + 2];       \
    g10 = sb[o_ + ro1]; g11 = sb[o_ + ro1 + 1]; g12 = sb[o_ + ro1 + 2];       \
    g20 = sb[o_ + ro2]; g21 = sb[o_ + ro2 + 1]; g22 = sb[o_ + ro2 + 2];       \
} while (0)

#define PREFETCH_M(P) do {                                                    \
    const int pc_ = (P) < 0 ? 0 : ((P) > ND - 1 ? ND - 1 : (P));              \
    const float pm_ = ((P) >= 0 && (P) < ND) ? 1.f : 0.f;                     \
    const int o_ = pc_ * PLI;                                                 \
    g00 = sb[o_ + ro0] * pm_; g01 = sb[o_ + ro0 + 1] * pm_; g02 = sb[o_ + ro0 + 2] * pm_; \
    g10 = sb[o_ + ro1] * pm_; g11 = sb[o_ + ro1 + 1] * pm_; g12 = sb[o_ + ro1 + 2] * pm_; \
    g20 = sb[o_ + ro2] * pm_; g21 = sb[o_ + ro2 + 1] * pm_; g22 = sb[o_ + ro2 + 2] * pm_; \
} while (0)

#define STAGE_WRITE() do {                                                    \
    ldw[0] = g00; ldw[1] = g01; ldw[2] = g02;                                 \
    ldw[LDSW + 0] = g10; ldw[LDSW + 1] = g11; ldw[LDSW + 2] = g12;            \
    ldw[2 * LDSW + 0] = g20; ldw[2 * LDSW + 1] = g21; ldw[2 * LDSW + 2] = g22;\
} while (0)

// h-FIRST separable pass of tensor T into slot SP (all weights unscaled):
//   u = x[h-1] + 2x[h] + x[h+1],  v = x[h+1] - x[h-1]  on the 5-elem window,
//   then ss = smooth_w(u), ts = smooth_w(v), st = sobel_w(u). Direct assign.
#define TPASS(T, SP) do {                                                     \
    const float* r0_ = RPTR(T, 0);                                            \
    const float* r1_ = RPTR(T, 1);                                            \
    const float* r2_ = RPTR(T, 2);                                            \
    float u0_, u1_, u2_, u3_, u4_, v0_, v1_, v2_, v3_, v4_;                   \
    { const float a_ = r0_[-1], b_ = r1_[-1], c_ = r2_[-1];                   \
      u0_ = fmaf(2.f, b_, a_ + c_); v0_ = c_ - a_; }                          \
    { const float a_ = r0_[0],  b_ = r1_[0],  c_ = r2_[0];                    \
      u1_ = fmaf(2.f, b_, a_ + c_); v1_ = c_ - a_; }                          \
    { const float a_ = r0_[1],  b_ = r1_[1],  c_ = r2_[1];                    \
      u2_ = fmaf(2.f, b_, a_ + c_); v2_ = c_ - a_; }                          \
    { const float a_ = r0_[2],  b_ = r1_[2],  c_ = r2_[2];                    \
      u3_ = fmaf(2.f, b_, a_ + c_); v3_ = c_ - a_; }                          \
    { const float a_ = r0_[3],  b_ = r1_[3],  c_ = r2_[3];                    \
      u4_ = fmaf(2.f, b_, a_ + c_); v4_ = c_ - a_; }                          \
    q[T][SP][0][0] = fmaf(2.f, u1_, u0_ + u2_);                               \
    q[T][SP][0][1] = fmaf(2.f, u2_, u1_ + u3_);                               \
    q[T][SP][0][2] = fmaf(2.f, u3_, u2_ + u4_);                               \
    q[T][SP][1][0] = fmaf(2.f, v1_, v0_ + v2_);                               \
    q[T][SP][1][1] = fmaf(2.f, v2_, v1_ + v3_);                               \
    q[T][SP][1][2] = fmaf(2.f, v3_, v2_ + v4_);                               \
    q[T][SP][2][0] = u2_ - u0_;                                               \
    q[T][SP][2][1] = u3_ - u1_;                                               \
    q[T][SP][2][2] = u4_ - u2_;                                               \
} while (0)

// phase: R9's proven 2-barrier structure, verbatim
#define PROCESS(SP, PNEXT) do {                                               \
    __syncthreads();                                                          \
    STAGE_WRITE();                                                            \
    __syncthreads();                                                          \
    PREFETCH(PNEXT);                                                          \
    TPASS(0, SP); TPASS(1, SP);                                               \
} while (0)

#define PROCESS_M(SP, PNEXT) do {                                             \
    __syncthreads();                                                          \
    STAGE_WRITE();                                                            \
    __syncthreads();                                                          \
    PREFETCH_M(PNEXT);                                                        \
    TPASS(0, SP); TPASS(1, SP);                                               \
} while (0)

#define PROCESS_LAST(SP) do {                                                 \
    __syncthreads();                                                          \
    STAGE_WRITE();                                                            \
    __syncthreads();                                                          \
    TPASS(0, SP); TPASS(1, SP);                                               \
} while (0)

// unscaled magnitude: all conv scales are exactly 16x -> e_u = 16 e;
// eps_u = 256 * 1e-8; fast v_sqrt_f32 (1 inst, ~1ulp)
#define EDGE1(T, J, SM, SC, SP, E) do {                                       \
    const float gx_ = fmaf(2.f, q[T][SC][2][J], q[T][SM][2][J] + q[T][SP][2][J]); \
    const float gy_ = fmaf(2.f, q[T][SC][1][J], q[T][SM][1][J] + q[T][SP][1][J]); \
    const float gz_ = q[T][SP][0][J] - q[T][SM][0][J];                        \
    const float d_ = fmaf(gz_, gz_, fmaf(gy_, gy_, fmaf(gx_, gx_, 2.56e-6f)));\
    asm("v_sqrt_f32 %0, %1" : "=v"(E) : "v"(d_));                             \
} while (0)

#define EMIT(SM, SC, SP) do {                                                 \
    float e0_, e1_;                                                           \
    EDGE1(0, 0, SM, SC, SP, e0_); EDGE1(1, 0, SM, SC, SP, e1_); acc += fabsf(e0_ - e1_); \
    EDGE1(0, 1, SM, SC, SP, e0_); EDGE1(1, 1, SM, SC, SP, e1_); acc += fabsf(e0_ - e1_); \
    EDGE1(0, 2, SM, SC, SP, e0_); EDGE1(1, 2, SM, SC, SP, e1_); acc += fabsf(e0_ - e1_); \
} while (0)

    // prologue: plane d0-1 -> slot 0, plane d0 -> slot 1
    PREFETCH_M(d0 - 1);
    PROCESS(0, d0);          // computes plane d0-1
    PROCESS(1, d0 + 1);      // computes plane d0

    // steady state: 5 groups x 3 phases; computed planes d0+1 .. d0+15
    for (int gg = 0; gg < 4; ++gg) {
        const int p = d0 + 1 + gg * 3;
        PROCESS(2, p + 1); EMIT(0, 1, 2);   // emit output plane d0+3*gg
        PROCESS(0, p + 2); EMIT(1, 2, 0);
        PROCESS(1, p + 3); EMIT(2, 0, 1);
    }
    PROCESS(2, d0 + 14);   EMIT(0, 1, 2);
    PROCESS(0, d0 + 15);   EMIT(1, 2, 0);
    PROCESS_M(1, d0 + 16); EMIT(2, 0, 1);   // prefetch plane may be OOB
    PROCESS_LAST(2);       EMIT(0, 1, 2);   // computes plane d0+16 (masked)

#undef RPTR
#undef PREFETCH
#undef PREFETCH_M
#undef STAGE_WRITE
#undef TPASS
#undef PROCESS
#undef PROCESS_M
#undef PROCESS_LAST
#undef EDGE1
#undef EMIT

    // wave reduce -> block reduce -> one atomic per block
    #pragma unroll
    for (int off = 32; off > 0; off >>= 1)
        acc += __shfl_down(acc, off, 64);
    if (lane == 0) wsum[wid] = acc;
    __syncthreads();
    if (threadIdx.x == 0) {
        // fold the exact 1/16 kernel scale and the mean into one constant
        const float invN = 1.f / (16.f * (float)((long long)NB * ND * NH * NW));
        atomicAdd(out, (wsum[0] + wsum[1] + wsum[2] + wsum[3]) * invN);
    }
}

} // namespace

extern "C" void kernel_launch(void* const* d_in, const int* in_sizes, int n_in,
                              void* d_out, int out_size, void* d_ws, size_t ws_size,
                              hipStream_t stream) {
    const float* pred = (const float*)d_in[0];
    const float* targ = (const float*)d_in[1];
    float* out = (float*)d_out;
    (void)in_sizes; (void)n_in; (void)out_size; (void)d_ws; (void)ws_size;

    hipMemsetAsync(out, 0, sizeof(float), stream);

    dim3 grid(ND / CD, NH / 4, NB);   // (8, 48, 4) = 1536 blocks, 6/CU
    dim3 block(256);
    edge_loss3d<<<grid, block, 0, stream>>>(pred, targ, out);
}